// Round 1
// baseline (169.609 us; speedup 1.0000x reference)
//
#include <hip/hip_runtime.h>

// Problem constants (fixed by the reference).
#define NS 4
#define NA 8192
#define NTOK 1024
#define NC 8
#define THREADS 256
#define JSLOTS 4
#define JPB (THREADS * JSLOTS)   // 1024 j-atoms per block (= one chain)
#define TI 64                    // i-atoms per block
#define TPJ (JPB / TI)           // 16 i-tiles per j-tile
// Strict-triangle grid: only blocks with i-tile entirely before the j-tile's
// chain. Active blocks per sample = sum_{jb=1..7} jb*16 = 448. Diagonal
// (same-chain) tiles only feed the masked counts[a][a] -> never scheduled.
#define GRIDX 448
#define NBLOCKS (GRIDX * NS)

typedef float v2f __attribute__((ext_vector_type(2)));

// ws layout:
//   staged[NS*NA] float4 : (2x, 2y, 2z, 2*(thr^2 - sq)) per (s, atom)
//   chain[NA]     int    : per-atom chain id
//   counts[257]   int    : [0..255] global accumulators, [256] done-ticket
//                          (all zeroed by setup each iteration)

__global__ __launch_bounds__(THREADS)
void setup_kernel(const float* __restrict__ coords, const int* __restrict__ asym,
                  const int* __restrict__ a2t, float4* __restrict__ staged,
                  int* __restrict__ chain, int* __restrict__ counts) {
  const float THR2 = 1.21f;  // 1.1^2
  int idx = blockIdx.x * THREADS + threadIdx.x;  // grid covers NS*NA
  float x = coords[3 * idx + 0], y = coords[3 * idx + 1], z = coords[3 * idx + 2];
  staged[idx] = make_float4(2.0f * x, 2.0f * y, 2.0f * z,
                            2.0f * (THR2 - (x * x + y * y + z * z)));
  if (idx < NA) chain[idx] = asym[a2t[idx]];
  if (idx < NS * NC * NC + 1) counts[idx] = 0;  // 256 counts + done ticket
}

// Ballot/popc accumulation (best measured form, R9). This revision packs the
// 4 j-slots into 2x float2 so the dot-product chain can map to v_pk_fma_f32
// (VOP3P dual-fp32): per t, 6 pk_fma + 4 v_cmp instead of 12 fma + 4 v_cmp.
// Identical fma operations/order => bit-identical counts vs the scalar form.
// Finalize is merged in via a last-block ticket (saves one graph launch).
__global__ __launch_bounds__(THREADS, 7)
void clash_kernel(const float4* __restrict__ staged, const int* __restrict__ chain,
                  const int* __restrict__ asym, int* __restrict__ counts,
                  float* __restrict__ out) {
  __shared__ int red[NC * NC];
  __shared__ int hist[NC];
  __shared__ int lastFlag;

  const int tid = threadIdx.x;
  const int s = blockIdx.z;
  int* done = counts + NS * NC * NC;  // ticket at counts[256]

  // Decode strict-triangle block index. cum(jb) = 8*jb*(jb-1) blocks precede
  // j-tile jb; jb ranges 1..7, ib in [0, jb*16).
  int f = blockIdx.x, jb = 1;
  while (f >= 8 * jb * (jb + 1)) ++jb;
  const int ib = f - 8 * jb * (jb - 1);

  if (tid < NC * NC) red[tid] = 0;

  const float4* __restrict__ sb = staged + (size_t)s * NA;
  const float TWO_THR2 = 2.42f;  // 2*1.1^2

  // Per-thread j-atoms (4 slots), coalesced float4 loads from staged.
  // Packed as 2x float2 (slot pairs {0,1} and {2,3}) for v_pk_fma_f32.
  v2f jx2[2], jy2[2], jz2[2], jt2[2];
  int bj[JSLOTS];
#pragma unroll
  for (int u = 0; u < JSLOTS; ++u) {
    int j = jb * JPB + u * THREADS + tid;
    float4 cj = sb[j];
    jx2[u >> 1][u & 1] = cj.x;               // = 2*x_j etc.
    jy2[u >> 1][u & 1] = cj.y;
    jz2[u >> 1][u & 1] = cj.z;
    jt2[u >> 1][u & 1] = TWO_THR2 - cj.w;    // = 2*sq_j
    bj[u] = chain[j];
  }

  // i-tile chain id + uniformity: per-lane global read + wave votes (no LDS).
  int myi = chain[ib * TI + (tid & 63)];
  const int A = __builtin_amdgcn_readfirstlane(myi);
  bool uniform = __all(myi == A);

  int b0[JSLOTS];
#pragma unroll
  for (int u = 0; u < JSLOTS; ++u) {
    b0[u] = __builtin_amdgcn_readfirstlane(bj[u]);
    uniform = uniform && __all(bj[u] == b0[u]);
  }

  __syncthreads();  // red[] init visible to all waves

  // i-tile via wave-uniform scalar loads (s_load_dwordx4), LDS pipe idle.
  const float4* __restrict__ tg = sb + ib * TI;

  // clash <=> (2xi)(2xj)+(2yi)(2yj)+(2zi)(2zj) + 2*(thr2-sq_i) > 2*sq_j
  if (uniform) {
    int acc[JSLOTS] = {0, 0, 0, 0};
#pragma unroll 8
    for (int t = 0; t < TI; ++t) {
      float4 ci = tg[t];
      v2f cx = {ci.x, ci.x}, cy = {ci.y, ci.y};
      v2f cz = {ci.z, ci.z}, cw = {ci.w, ci.w};
#pragma unroll
      for (int p = 0; p < 2; ++p) {
        v2f d = __builtin_elementwise_fma(cx, jx2[p],
                __builtin_elementwise_fma(cy, jy2[p],
                __builtin_elementwise_fma(cz, jz2[p], cw)));
        acc[2 * p + 0] += __popcll(__ballot(d.x > jt2[p].x));
        acc[2 * p + 1] += __popcll(__ballot(d.y > jt2[p].y));
      }
    }
    if ((tid & 63) == 0) {
#pragma unroll
      for (int u = 0; u < JSLOTS; ++u) {
        if (acc[u]) {
          atomicAdd(&red[A * NC + b0[u]], acc[u]);
          atomicAdd(&red[b0[u] * NC + A], acc[u]);  // strict blocks: mirror
        }
      }
    }
  } else {
    // robustness path (not hit with this data layout)
    for (int t = 0; t < TI; ++t) {
      float4 ci = tg[t];
      int a = chain[ib * TI + t];
#pragma unroll
      for (int u = 0; u < JSLOTS; ++u) {
        float xu = jx2[u >> 1][u & 1], yu = jy2[u >> 1][u & 1];
        float zu = jz2[u >> 1][u & 1], tu = jt2[u >> 1][u & 1];
        float d = fmaf(ci.x, xu, fmaf(ci.y, yu, fmaf(ci.z, zu, ci.w)));
        if (d > tu) {
          atomicAdd(&red[a * NC + bj[u]], 1);
          atomicAdd(&red[bj[u] * NC + a], 1);
        }
      }
    }
  }

  __syncthreads();
  if (tid < NC * NC) {
    int v = red[tid];
    if (v) atomicAdd(&counts[s * NC * NC + tid], v);
  }

  // ---- last-block finalize (replaces the separate finalize launch) ----
  __threadfence();   // order this block's count atomics before the ticket
  __syncthreads();
  if (tid == 0) lastFlag = (atomicAdd(done, 1) == NBLOCKS - 1);
  __syncthreads();
  if (!lastFlag) return;

  // All other blocks have fenced + ticketed: counts is complete.
  if (tid < NC) hist[tid] = 0;
  __syncthreads();
  for (int t = tid; t < NTOK; t += THREADS) atomicAdd(&hist[asym[t]], NA / NTOK);
  __syncthreads();

  __threadfence();
  // Read via device-scope RMW so per-XCD L2 non-coherence can't serve stale.
  int c = atomicAdd(&counts[tid], 0);
  int a = (tid >> 3) & 7, b = tid & 7;
  float total = (a == b) ? 0.0f : (float)c;
  float minn = (float)min(hist[a], hist[b]);
  float rel = total / minn;
  out[tid] = ((total > 100.0f) || (rel > 0.5f)) ? 1.0f : 0.0f;
  out[256 + 2 * tid + 0] = total;
  out[256 + 2 * tid + 1] = rel;
}

extern "C" void kernel_launch(void* const* d_in, const int* in_sizes, int n_in,
                              void* d_out, int out_size, void* d_ws, size_t ws_size,
                              hipStream_t stream) {
  const float* coords = (const float*)d_in[0];  // [4, 8192, 3] f32
  const int* asym = (const int*)d_in[1];        // [1024] i32
  const int* a2t = (const int*)d_in[2];         // [8192] i32
  float* out = (float*)d_out;                   // 256 flags + 512 details

  float4* staged = (float4*)d_ws;               // [NS*NA]
  int* chain = (int*)(staged + NS * NA);        // [NA]
  int* counts = chain + NA;                     // [256 counts + 1 ticket]

  setup_kernel<<<dim3(NS * NA / THREADS), THREADS, 0, stream>>>(coords, asym, a2t,
                                                                staged, chain, counts);
  clash_kernel<<<dim3(GRIDX, 1, NS), THREADS, 0, stream>>>(staged, chain, asym,
                                                           counts, out);
}

// Round 2
// 77.551 us; speedup vs baseline: 2.1871x; 2.1871x over previous
//
#include <hip/hip_runtime.h>

// Problem constants (fixed by the reference).
#define NS 4
#define NA 8192
#define NTOK 1024
#define NC 8
#define THREADS 256
#define JSLOTS 4
#define JPB (THREADS * JSLOTS)   // 1024 j-atoms per block (= one chain)
#define TI 64                    // i-atoms per block
#define TPJ (JPB / TI)           // 16 i-tiles per j-tile
// Strict-triangle grid: only blocks with i-tile entirely before the j-tile's
// chain. Active blocks per sample = sum_{jb=1..7} jb*16 = 448. Diagonal
// (same-chain) tiles only feed the masked counts[a][a] -> never scheduled.
#define GRIDX 448

// ws layout:
//   staged[NS*NA] float4 : (2x, 2y, 2z, 2*(thr^2 - sq)) per (s, atom)
//   chain[NA]     int    : per-atom chain id
//   counts[NS*NC*NC] int : global accumulators (zeroed by setup)

// R11 lessons (reverted): (a) merging finalize via a per-block
// __threadfence() + ticket cost ~90us -- agent-scope fences on gfx950 emit
// buffer_wbl2/buffer_inv per block (non-coherent XCD L2s) and serialize;
// clash went 116us with VALUBusy 7.5%. (b) v_pk_fma_f32 packing of the
// j-slots needs the wave-uniform i-operands broadcast into 64-bit VGPR
// pairs (~8 v_mov per t), negating the fma savings. Scalar fma + ballot
// (R9 form) remains the best measured inner loop.

__global__ __launch_bounds__(THREADS)
void setup_kernel(const float* __restrict__ coords, const int* __restrict__ asym,
                  const int* __restrict__ a2t, float4* __restrict__ staged,
                  int* __restrict__ chain, int* __restrict__ counts) {
  const float THR2 = 1.21f;  // 1.1^2
  int idx = blockIdx.x * THREADS + threadIdx.x;  // grid covers NS*NA
  float x = coords[3 * idx + 0], y = coords[3 * idx + 1], z = coords[3 * idx + 2];
  staged[idx] = make_float4(2.0f * x, 2.0f * y, 2.0f * z,
                            2.0f * (THR2 - (x * x + y * y + z * z)));
  if (idx < NA) chain[idx] = asym[a2t[idx]];
  if (idx < NS * NC * NC) counts[idx] = 0;
}

// Ballot/popc accumulation (best measured form, R9): per (t,u) 4 VALU
// (3 fma + v_cmp->sgpr) + 2 SALU (s_bcnt1 + s_add), balanced across the
// vector and scalar pipes. i-tile via wave-uniform s_load_dwordx4; block
// LDS reduction red[] -> <=64 global atomics per block (per-wave global
// atomics were a 4.5x regression in R8; vcc-serialized v_addc asm regressed
// in R10; pk_fma packing and fence-merged finalize regressed in R11).
__global__ __launch_bounds__(THREADS, 8)
void clash_kernel(const float4* __restrict__ staged, const int* __restrict__ chain,
                  int* __restrict__ counts) {
  __shared__ int red[NC * NC];

  const int tid = threadIdx.x;
  const int s = blockIdx.z;

  // Decode strict-triangle block index. cum(jb) = 8*jb*(jb-1) blocks precede
  // j-tile jb; jb ranges 1..7, ib in [0, jb*16).
  int f = blockIdx.x, jb = 1;
  while (f >= 8 * jb * (jb + 1)) ++jb;
  const int ib = f - 8 * jb * (jb - 1);

  if (tid < NC * NC) red[tid] = 0;

  const float4* __restrict__ sb = staged + (size_t)s * NA;
  const float TWO_THR2 = 2.42f;  // 2*1.1^2

  // Per-thread j-atoms (4 slots), coalesced float4 loads from staged.
  float xj[JSLOTS], yj[JSLOTS], zj[JSLOTS], tj2[JSLOTS];
  int bj[JSLOTS];
#pragma unroll
  for (int u = 0; u < JSLOTS; ++u) {
    int j = jb * JPB + u * THREADS + tid;
    float4 cj = sb[j];
    xj[u] = cj.x; yj[u] = cj.y; zj[u] = cj.z;   // = 2*x_j etc.
    tj2[u] = TWO_THR2 - cj.w;                   // = 2*sq_j
    bj[u] = chain[j];
  }

  // i-tile chain id + uniformity: per-lane global read + wave votes (no LDS).
  int myi = chain[ib * TI + (tid & 63)];
  const int A = __builtin_amdgcn_readfirstlane(myi);
  bool uniform = __all(myi == A);

  int b0[JSLOTS];
#pragma unroll
  for (int u = 0; u < JSLOTS; ++u) {
    b0[u] = __builtin_amdgcn_readfirstlane(bj[u]);
    uniform = uniform && __all(bj[u] == b0[u]);
  }

  __syncthreads();  // red[] init visible to all waves

  // i-tile via wave-uniform scalar loads (s_load_dwordx4), LDS pipe idle.
  const float4* __restrict__ tg = sb + ib * TI;

  // clash <=> (2xi)(2xj)+(2yi)(2yj)+(2zi)(2zj) + 2*(thr2-sq_i) > 2*sq_j
  if (uniform) {
    int acc[JSLOTS] = {0, 0, 0, 0};
#pragma unroll 8
    for (int t = 0; t < TI; ++t) {
      float4 ci = tg[t];
#pragma unroll
      for (int u = 0; u < JSLOTS; ++u) {
        float d = fmaf(ci.x, xj[u], fmaf(ci.y, yj[u], fmaf(ci.z, zj[u], ci.w)));
        acc[u] += __popcll(__ballot(d > tj2[u]));  // v_cmp + s_bcnt1 + s_add
      }
    }
    if ((tid & 63) == 0) {
#pragma unroll
      for (int u = 0; u < JSLOTS; ++u) {
        if (acc[u]) {
          atomicAdd(&red[A * NC + b0[u]], acc[u]);
          atomicAdd(&red[b0[u] * NC + A], acc[u]);  // strict blocks: mirror
        }
      }
    }
  } else {
    // robustness path (not hit with this data layout)
    for (int t = 0; t < TI; ++t) {
      float4 ci = tg[t];
      int a = chain[ib * TI + t];
#pragma unroll
      for (int u = 0; u < JSLOTS; ++u) {
        float d = fmaf(ci.x, xj[u], fmaf(ci.y, yj[u], fmaf(ci.z, zj[u], ci.w)));
        if (d > tj2[u]) {
          atomicAdd(&red[a * NC + bj[u]], 1);
          atomicAdd(&red[bj[u] * NC + a], 1);
        }
      }
    }
  }

  __syncthreads();
  if (tid < NC * NC) {
    int v = red[tid];
    if (v) atomicAdd(&counts[s * NC * NC + tid], v);
  }
}

__global__ __launch_bounds__(THREADS)
void finalize_kernel(const int* __restrict__ asym, const int* __restrict__ counts,
                     float* __restrict__ out) {
  __shared__ int hist[NC];
  int tid = threadIdx.x;
  if (tid < NC) hist[tid] = 0;
  __syncthreads();
  for (int t = tid; t < NTOK; t += THREADS) atomicAdd(&hist[asym[t]], NA / NTOK);
  __syncthreads();

  // tid = s*64 + a*8 + b  (256 threads cover all entries)
  int c = counts[tid];
  int a = (tid >> 3) & 7, b = tid & 7;
  float total = (a == b) ? 0.0f : (float)c;
  float minn = (float)min(hist[a], hist[b]);
  float rel = total / minn;
  out[tid] = ((total > 100.0f) || (rel > 0.5f)) ? 1.0f : 0.0f;
  out[256 + 2 * tid + 0] = total;
  out[256 + 2 * tid + 1] = rel;
}

extern "C" void kernel_launch(void* const* d_in, const int* in_sizes, int n_in,
                              void* d_out, int out_size, void* d_ws, size_t ws_size,
                              hipStream_t stream) {
  const float* coords = (const float*)d_in[0];  // [4, 8192, 3] f32
  const int* asym = (const int*)d_in[1];        // [1024] i32
  const int* a2t = (const int*)d_in[2];         // [8192] i32
  float* out = (float*)d_out;                   // 256 flags + 512 details

  float4* staged = (float4*)d_ws;               // [NS*NA]
  int* chain = (int*)(staged + NS * NA);        // [NA]
  int* counts = chain + NA;                     // [NS*NC*NC]

  setup_kernel<<<dim3(NS * NA / THREADS), THREADS, 0, stream>>>(coords, asym, a2t,
                                                                staged, chain, counts);
  clash_kernel<<<dim3(GRIDX, 1, NS), THREADS, 0, stream>>>(staged, chain, counts);
  finalize_kernel<<<1, THREADS, 0, stream>>>(asym, counts, out);
}